// Round 10
// baseline (1677.448 us; speedup 1.0000x reference)
//
#include <hip/hip_runtime.h>
#include <stdint.h>

#define BB 256      // batch
#define TT 200      // timesteps
#define INN 1568    // inputs
#define OO 100      // outputs
#define PAIRS 784   // INN/2
#define NHALF 12800 // (BB*OO)/2
#define NBLK 240    // total grid: 172 chains-role + 68 pack-role, 1 block/CU
#define ROWSTRIDE (4 * INN)
#define DW 4        // chain waves per block

typedef unsigned long long u64;
typedef __attribute__((ext_vector_type(4))) int v4i;

// async global->LDS (16 B/lane); dest = wave-uniform base + lane*16
typedef const __attribute__((address_space(1))) uint32_t* gas_p;
typedef __attribute__((address_space(3))) uint32_t* las_p;
#define GLD16(g, l) __builtin_amdgcn_global_load_lds((gas_p)(g), (las_p)(l), 16, 0, 0)

// ---------------- threefry2x32 (JAX-compatible) ----------------
__device__ __forceinline__ void tf_round(uint32_t& x0, uint32_t& x1, int r) {
    x0 += x1;
    x1 = (x1 << r) | (x1 >> (32 - r));
    x1 ^= x0;
}

__device__ __forceinline__ void threefry(uint32_t k0, uint32_t k1,
                                         uint32_t x0, uint32_t x1,
                                         uint32_t& o0, uint32_t& o1) {
    uint32_t k2 = k0 ^ k1 ^ 0x1BD11BDAu;
    x0 += k0; x1 += k1;
    tf_round(x0,x1,13); tf_round(x0,x1,15); tf_round(x0,x1,26); tf_round(x0,x1,6);
    x0 += k1; x1 += k2 + 1u;
    tf_round(x0,x1,17); tf_round(x0,x1,29); tf_round(x0,x1,16); tf_round(x0,x1,24);
    x0 += k2; x1 += k0 + 2u;
    tf_round(x0,x1,13); tf_round(x0,x1,15); tf_round(x0,x1,26); tf_round(x0,x1,6);
    x0 += k0; x1 += k1 + 3u;
    tf_round(x0,x1,17); tf_round(x0,x1,29); tf_round(x0,x1,16); tf_round(x0,x1,24);
    x0 += k1; x1 += k2 + 4u;
    tf_round(x0,x1,13); tf_round(x0,x1,15); tf_round(x0,x1,26); tf_round(x0,x1,6);
    o0 = x0 + k2; o1 = x1 + k0 + 5u;
}

// flags layout (zeroed by k_zero, 64 words):
//   [0] pack unit claim queue   [1] winners-done (->100)
//   [2] fwpost-done (->100)     [8+tc] tc row-group done (->4), tc<50
#define F_CLAIM 0
#define F_WIN   1
#define F_FW    2
#define F_TC    8

__global__ __launch_bounds__(64) void k_zero(uint32_t* __restrict__ flags) {
    flags[threadIdx.x] = 0;
}

// ---------------- LDS (roles/phases time-separated) ----------------
struct ChSM {
    u64 rows[DW][32][64];           // [wave][t&31][k*8+pl]      64 KB
    u64 wp[DW][16][128];            // [wave][t&15][win64|post64] 64 KB
    u64 potC[DW][2][8][10];         //                             5 KB
    u64 ltpC[DW][2][8][10];         //                             5 KB
    uint32_t cntR[DW][16][16];      //                             4 KB
};                                  // 142 KB -> 1 block/CU
struct FwSM { uint32_t wl32[TT * 65]; int fwl[BB]; };   // 53 KB
union SMem { ChSM c; FwSM w; };

__global__ __launch_bounds__(512, 1) void k_mono(
        const int* __restrict__ x,
        const float* __restrict__ L0,
        const float* __restrict__ p0arr,
        uint32_t* __restrict__ flags,
        uint8_t* __restrict__ widx,
        uint32_t* __restrict__ cntg,
        u64* __restrict__ winbits,
        u64* __restrict__ postbits,
        u64* __restrict__ bitB,
        float* __restrict__ outL,
        float* __restrict__ outp) {
    __shared__ SMem sm;
    __shared__ uint32_t smclaim;
    const int tid = threadIdx.x;
    const int bid = blockIdx.x;

    // ================= PACK role: blocks 172..239 ==========================
    // Register-batched streaming (R5-proven), tc-major atomic queue; per-unit
    // done-flag lets chains consume rows while later units still stream.
    if (bid >= 172) {
        const v4i* xp = (const v4i*)x;
        for (;;) {
            __syncthreads();
            if (tid == 0)
                smclaim = __hip_atomic_fetch_add(&flags[F_CLAIM], 1u,
                              __ATOMIC_RELAXED, __HIP_MEMORY_SCOPE_AGENT);
            __syncthreads();
            uint32_t u = smclaim;
            if (u >= 200u) break;
            int wb = (int)(u & 3), tc = (int)(u >> 2);   // tc-major order
            u64 acc[4][4];
            #pragma unroll
            for (int q = 0; q < 4; ++q)
                #pragma unroll
                for (int c = 0; c < 4; ++c) acc[q][c] = 0;
            bool x4 = (tid < 32);          // 1568 = 3*512 + 32
            for (int blb = 0; blb < 64; blb += 4) {
                v4i v[4][3];
                v4i vt[4];
                #pragma unroll
                for (int s4 = 0; s4 < 4; ++s4) {
                    size_t base = ((size_t)((wb * 64 + blb + s4) * TT + tc * 4)) * 392;
                    #pragma unroll
                    for (int q = 0; q < 3; ++q)
                        v[s4][q] = __builtin_nontemporal_load(&xp[base + tid + q * 512]);
                    if (x4)
                        vt[s4] = __builtin_nontemporal_load(&xp[base + tid + 1536]);
                }
                #pragma unroll
                for (int s4 = 0; s4 < 4; ++s4) {
                    u64 bit = 1ull << (blb + s4);
                    #pragma unroll
                    for (int q = 0; q < 3; ++q) {
                        if (v[s4][q].x) acc[q][0] |= bit;
                        if (v[s4][q].y) acc[q][1] |= bit;
                        if (v[s4][q].z) acc[q][2] |= bit;
                        if (v[s4][q].w) acc[q][3] |= bit;
                    }
                    if (x4) {
                        if (vt[s4].x) acc[3][0] |= bit;
                        if (vt[s4].y) acc[3][1] |= bit;
                        if (vt[s4].z) acc[3][2] |= bit;
                        if (vt[s4].w) acc[3][3] |= bit;
                    }
                }
            }
            #pragma unroll
            for (int q = 0; q < 4; ++q) {
                if (q == 3 && !x4) continue;
                int p = tid + q * 512;
                int tp = (p >= 1176) ? 3 : (p >= 784) ? 2 : (p >= 392) ? 1 : 0;
                int iq = p - tp * 392;
                u64* dst = bitB + ((size_t)((tc * 4 + tp) * 4 + wb)) * INN + iq * 4;
                dst[0] = acc[q][0]; dst[1] = acc[q][1];
                dst[2] = acc[q][2]; dst[3] = acc[q][3];
            }
            __syncthreads();
            if (tid == 0) {
                __threadfence();   // release rows before flag
                __hip_atomic_fetch_add(&flags[F_TC + tc], 1u,
                    __ATOMIC_ACQ_REL, __HIP_MEMORY_SCOPE_AGENT);
            }
        }
        return;
    }

    // ================= chains-role blocks 0..171 ===========================
    if (bid < 100) {
        {   // ---- winners: idx = bid*512+tid (100*512 = TT*BB) ----
            int idx = bid * 512 + tid;
            int t = idx >> 8, b = idx & 255;
            uint32_t fk0, fk1;
            threefry(0u, 42u, 0u, (uint32_t)t, fk0, fk1);
            uint32_t bestkey = 0u;
            int bo = 0;
            int nbase = b * OO;
            for (int o = 0; o < OO; ++o) {
                uint32_t n = (uint32_t)(nbase + o);
                uint32_t lo = (n < NHALF) ? n : n - NHALF;
                uint32_t v0, v1;
                threefry(fk0, fk1, lo, lo + NHALF, v0, v1);
                uint32_t bits = (n < NHALF) ? v0 : v1;
                uint32_t key = bits >> 9;
                if (key > bestkey) { bestkey = key; bo = o; }
            }
            widx[idx] = (uint8_t)bo;
        }
        __syncthreads();
        if (tid == 0) {     // publish + wait all winners
            __threadfence();
            __hip_atomic_fetch_add(&flags[F_WIN], 1u,
                __ATOMIC_ACQ_REL, __HIP_MEMORY_SCOPE_AGENT);
            while (__hip_atomic_load(&flags[F_WIN], __ATOMIC_ACQUIRE,
                                     __HIP_MEMORY_SCOPE_AGENT) < 100u)
                __builtin_amdgcn_s_sleep(8);
            __threadfence();
        }
        __syncthreads();
        {   // ---- fwpost for o = bid (512-thread form, proven) ----
            const uint32_t* wsrc = (const uint32_t*)widx;
            for (int g = tid; g < TT * 64; g += 512)
                sm.w.wl32[(g >> 6) * 65 + (g & 63)] = wsrc[g];
            __syncthreads();
            int o = bid;
            if (tid < 64) {
                int f0 = 255, f1 = 255, f2 = 255, f3 = 255;
                for (int t = 0; t < TT; ++t) {
                    uint32_t w4 = sm.w.wl32[t * 65 + tid];
                    if (((w4      ) & 255u) == (uint32_t)o && f0 == 255) f0 = t;
                    if (((w4 >>  8) & 255u) == (uint32_t)o && f1 == 255) f1 = t;
                    if (((w4 >> 16) & 255u) == (uint32_t)o && f2 == 255) f2 = t;
                    if (((w4 >> 24) & 255u) == (uint32_t)o && f3 == 255) f3 = t;
                }
                sm.w.fwl[4 * tid + 0] = f0; sm.w.fwl[4 * tid + 1] = f1;
                sm.w.fwl[4 * tid + 2] = f2; sm.w.fwl[4 * tid + 3] = f3;
            }
            __syncthreads();
            if (tid < TT) {
                int t = tid;
                u64 wbA[4], pbA[4];
                uint32_t c = 0;
                #pragma unroll
                for (int k = 0; k < 4; ++k) {
                    u64 wacc = 0, pacc = 0;
                    for (int q2 = 0; q2 < 16; ++q2) {
                        uint32_t w4 = sm.w.wl32[t * 65 + k * 16 + q2];
                        #pragma unroll
                        for (int j = 0; j < 4; ++j) {
                            int bl = q2 * 4 + j;
                            bool win = (((w4 >> (8 * j)) & 255u) == (uint32_t)o);
                            c += win ? 1u : 0u;
                            bool post = (sm.w.fwl[k * 64 + q2 * 4 + j] < t) && !win;
                            u64 bit = 1ull << bl;
                            if (win)  wacc |= bit;
                            if (post) pacc |= bit;
                        }
                    }
                    wbA[k] = wacc; pbA[k] = pacc;
                }
                size_t base = (size_t)(t * OO + o) * 4;
                #pragma unroll
                for (int k = 0; k < 4; ++k) {
                    winbits[base + k] = wbA[k];
                    postbits[base + k] = pbA[k];
                }
                cntg[t * OO + o] = c;
            }
            __syncthreads();
            if (tid == 0) {
                __threadfence();
                __hip_atomic_fetch_add(&flags[F_FW], 1u,
                    __ATOMIC_ACQ_REL, __HIP_MEMORY_SCOPE_AGENT);
            }
        }
    }

    const int wv = tid >> 6, lane = tid & 63;
    if (wv >= DW) return;                       // waves 4..7 done
    int u = bid * DW + wv;                      // 0..687
    if (u >= 687) return;                       // 687 idle

    // wave-level wait: all fwpost done (wp/cnt readable)
    while (__hip_atomic_load(&flags[F_FW], __ATOMIC_ACQUIRE,
                             __HIP_MEMORY_SCOPE_AGENT) < 100u)
        __builtin_amdgcn_s_sleep(8);
    __threadfence();

    if (u == 686) {                             // ---- prior chain ----
        int l = lane;
        bool has2 = (l + 64) < OO;
        float pa = p0arr[l];
        float pb = has2 ? p0arr[l + 64] : -1e30f;
        auto norm = [&]() {
            pa = fminf(fmaxf(pa, -5.0f), 0.0f);
            if (has2) pb = fminf(fmaxf(pb, -5.0f), 0.0f);
            float mx = has2 ? fmaxf(pa, pb) : pa;
            #pragma unroll
            for (int s = 32; s > 0; s >>= 1) mx = fmaxf(mx, __shfl_xor(mx, s, 64));
            float smv = expf(pa - mx) + (has2 ? expf(pb - mx) : 0.0f);
            #pragma unroll
            for (int s = 32; s > 0; s >>= 1) smv += __shfl_xor(smv, s, 64);
            float lse = logf(smv) + mx;
            pa -= lse;
            if (has2) pb -= lse;
        };
        norm();
        for (int t = 0; t < TT; ++t) {
            float eta = 0.001f / (float)(t + 1);
            float wma = (float)cntg[t * OO + l] * (1.0f / 256.0f);
            pa += eta * ((-5.0f * pa - 1.0f) * wma - (1.0f - wma));
            if (has2) {
                float wmb = (float)cntg[t * OO + l + 64] * (1.0f / 256.0f);
                pb += eta * ((-5.0f * pb - 1.0f) * wmb - (1.0f - wmb));
            }
            norm();
        }
        outp[l] = pa;
        if (has2) outp[l + 64] = pb;
        return;
    }

    // ---- weight chains (R9 form) with per-tc row gating ----
    const int pg = u % 98, og = u / 98;         // og 0..6
    const int p0 = pg * 8, o0 = og * 16;
    const int pl = lane & 7, ol = lane >> 3;
    const int oA = o0 + ol, oB = oA + 8;
    const int i0 = p0 + pl, i1 = i0 + PAIRS;
    const bool actA = (oA < OO), actB = (oB < OO);

    const int e0 = (lane & 31) * 2;
    const int wk0 = e0 >> 3, wpl0 = e0 & 7;
    const u64* rowg = bitB + (size_t)((wk0 & 3) * INN + (wk0 >> 2) * PAIRS
                                      + p0 + wpl0);
    const int lw = lane & 31;
    const u64* wpg = (lane < 32) ? winbits : postbits;
    const bool wpact = (o0 + (lw >> 1)) < OO;
    const bool cntact = (lane < 8) && ((o0 + (lane & 3) * 4) < OO);

    int done_tc = -1;                           // contiguous tc watermark
    auto wait_tc = [&](int need) {
        if (done_tc >= need) return;
        for (;;) {
            uint32_t v = __hip_atomic_load(&flags[F_TC + done_tc + 1],
                            __ATOMIC_ACQUIRE, __HIP_MEMORY_SCOPE_AGENT);
            if (v >= 4u) { if (++done_tc >= need) break; }
            else __builtin_amdgcn_s_sleep(4);
        }
        __threadfence();
    };

    auto issueG = [&](int G) {
        int r0 = 2 * G;
        {
            int rr = r0 + (lane >> 5); if (rr > TT - 1) rr = TT - 1;
            GLD16(rowg + (size_t)rr * ROWSTRIDE,
                  (las_p)&sm.c.rows[wv][r0 & 31][0]);
        }
        {
            int rr = r0; if (rr > TT - 1) rr = TT - 1;
            if (wpact)
                GLD16(wpg + ((size_t)rr * OO + o0) * 4 + 2 * lw,
                      (las_p)&sm.c.wp[wv][r0 & 15][0]);
        }
        {
            int rr = r0 + 1; if (rr > TT - 1) rr = TT - 1;
            if (wpact)
                GLD16(wpg + ((size_t)rr * OO + o0) * 4 + 2 * lw,
                      (las_p)&sm.c.wp[wv][(r0 + 1) & 15][0]);
        }
        {
            if (cntact) {
                int rr = r0 + (lane >> 2); if (rr > TT - 1) rr = TT - 1;
                GLD16(cntg + (size_t)rr * OO + o0 + (lane & 3) * 4,
                      (las_p)&sm.c.cntR[wv][r0 & 15][0]);
            }
        }
    };

    float aA = actA ? L0[(size_t)i0 * OO + oA] : -1.0f;
    float bA = actA ? L0[(size_t)i1 * OO + oA] : -1.0f;
    float aB = actB ? L0[(size_t)i0 * OO + oB] : -1.0f;
    float bB = actB ? L0[(size_t)i1 * OO + oB] : -1.0f;
    {
        aA = fminf(fmaxf(aA, -5.0f), 0.0f);
        bA = fminf(fmaxf(bA, -5.0f), 0.0f);
        float m = fmaxf(aA, bA), mn = fminf(aA, bA);
        float lse = __logf(1.0f + __expf(mn - m)) + m;
        aA -= lse; bA -= lse;
        aB = fminf(fmaxf(aB, -5.0f), 0.0f);
        bB = fminf(fmaxf(bB, -5.0f), 0.0f);
        float m2 = fmaxf(aB, bB), mn2 = fminf(aB, bB);
        float lse2 = __logf(1.0f + __expf(mn2 - m2)) + m2;
        aB -= lse2; bB -= lse2;
    }

    auto chainstep = [&](int t, int sp) {
        int s = t & 15;
        const u64* wpS = &sm.c.wp[wv][s][0];
        const u64* P = sm.c.potC[wv][sp][pl];
        const u64* Lt = sm.c.ltpC[wv][sp][pl];
        u64 P0 = P[0], P1 = P[1], P2 = P[2], P3 = P[3];
        u64 P4 = P[4], P5 = P[5], P6 = P[6], P7 = P[7];
        u64 Q0 = Lt[0], Q1 = Lt[1], Q2 = Lt[2], Q3 = Lt[3];
        u64 Q4 = Lt[4], Q5 = Lt[5], Q6 = Lt[6], Q7 = Lt[7];
        float eta = 0.001f / (float)(t + 1);
        {
            u64 W0 = wpS[ol*4+0], W1 = wpS[ol*4+1], W2 = wpS[ol*4+2], W3 = wpS[ol*4+3];
            u64 S0 = wpS[64+ol*4+0], S1 = wpS[64+ol*4+1], S2 = wpS[64+ol*4+2], S3 = wpS[64+ol*4+3];
            float cw = (float)sm.c.cntR[wv][s][ol];
            float lt0 = (float)(__popcll(Q0&W0)+__popcll(Q1&W1)+__popcll(Q2&W2)+__popcll(Q3&W3));
            float lt1 = (float)(__popcll(Q4&W0)+__popcll(Q5&W1)+__popcll(Q6&W2)+__popcll(Q7&W3));
            float pp0 = (float)(__popcll(P0&S0)+__popcll(P1&S1)+__popcll(P2&S2)+__popcll(P3&S3));
            float pp1 = (float)(__popcll(P4&S0)+__popcll(P5&S1)+__popcll(P6&S2)+__popcll(P7&S3));
            float dw0 = (5.0f*__expf(-aA) - 1.0f)*(lt0*(1.0f/256.0f))
                      + (cw - lt0 - pp0)*(1.0f/256.0f);
            float dw1 = (5.0f*__expf(-bA) - 1.0f)*(lt1*(1.0f/256.0f))
                      + (cw - lt1 - pp1)*(1.0f/256.0f);
            aA += eta*dw0; bA += eta*dw1;
            aA = fminf(fmaxf(aA,-5.0f),0.0f);
            bA = fminf(fmaxf(bA,-5.0f),0.0f);
            float m = fmaxf(aA,bA), mn = fminf(aA,bA);
            float lse = __logf(1.0f + __expf(mn-m)) + m;
            aA -= lse; bA -= lse;
        }
        {
            u64 W0 = wpS[(ol+8)*4+0], W1 = wpS[(ol+8)*4+1], W2 = wpS[(ol+8)*4+2], W3 = wpS[(ol+8)*4+3];
            u64 S0 = wpS[64+(ol+8)*4+0], S1 = wpS[64+(ol+8)*4+1], S2 = wpS[64+(ol+8)*4+2], S3 = wpS[64+(ol+8)*4+3];
            float cw = (float)sm.c.cntR[wv][s][ol+8];
            float lt0 = (float)(__popcll(Q0&W0)+__popcll(Q1&W1)+__popcll(Q2&W2)+__popcll(Q3&W3));
            float lt1 = (float)(__popcll(Q4&W0)+__popcll(Q5&W1)+__popcll(Q6&W2)+__popcll(Q7&W3));
            float pp0 = (float)(__popcll(P0&S0)+__popcll(P1&S1)+__popcll(P2&S2)+__popcll(P3&S3));
            float pp1 = (float)(__popcll(P4&S0)+__popcll(P5&S1)+__popcll(P6&S2)+__popcll(P7&S3));
            float dw0 = (5.0f*__expf(-aB) - 1.0f)*(lt0*(1.0f/256.0f))
                      + (cw - lt0 - pp0)*(1.0f/256.0f);
            float dw1 = (5.0f*__expf(-bB) - 1.0f)*(lt1*(1.0f/256.0f))
                      + (cw - lt1 - pp1)*(1.0f/256.0f);
            aB += eta*dw0; bB += eta*dw1;
            aB = fminf(fmaxf(aB,-5.0f),0.0f);
            bB = fminf(fmaxf(bB,-5.0f),0.0f);
            float m = fmaxf(aB,bB), mn = fminf(aB,bB);
            float lse = __logf(1.0f + __expf(mn-m)) + m;
            aB -= lse; bB -= lse;
        }
    };

    wait_tc(1);                                 // rows 0..7 ready
    issueG(0); issueG(1); issueG(2); issueG(3);
    for (int I = 0; I < 100; ++I) {
        int rmax = 2 * I + 9; if (rmax > TT - 1) rmax = TT - 1;
        wait_tc(rmax >> 2);                     // gate prefetch on producer
        issueG(I + 4);
        asm volatile("s_waitcnt vmcnt(16)" ::: "memory");  // group I resident
        int b0 = 2 * I;
        u64 com = 0;
        #pragma unroll
        for (int j = 8; j >= 0; --j) {
            int r = b0 - j; r = (r < 0) ? 0 : r;
            com |= sm.c.rows[wv][r & 31][lane];
        }
        int r9 = b0 - 9;   r9 = (r9 < 0) ? 0 : r9;
        int r10 = b0 - 10; r10 = (r10 < 0) ? 0 : r10;
        u64 v9  = sm.c.rows[wv][r9 & 31][lane];
        u64 v10 = sm.c.rows[wv][r10 & 31][lane];
        u64 vt2 = sm.c.rows[wv][(b0 + 1) & 31][lane];
        u64 pot1 = com | v9;
        u64 pot2 = com | vt2;
        sm.c.potC[wv][0][lane & 7][lane >> 3] = pot1;
        sm.c.potC[wv][1][lane & 7][lane >> 3] = pot2;
        sm.c.ltpC[wv][0][lane & 7][lane >> 3] = pot1 | v10;
        sm.c.ltpC[wv][1][lane & 7][lane >> 3] = pot2 | v9;
        asm volatile("s_waitcnt lgkmcnt(0)" ::: "memory");  // cross-lane publish
        chainstep(b0, 0);
        chainstep(b0 + 1, 1);
    }
    if (actA) {
        outL[(size_t)i0 * OO + oA] = aA;
        outL[(size_t)i1 * OO + oA] = bA;
    }
    if (actB) {
        outL[(size_t)i0 * OO + oB] = aB;
        outL[(size_t)i1 * OO + oB] = bB;
    }
}

extern "C" void kernel_launch(void* const* d_in, const int* in_sizes, int n_in,
                              void* d_out, int out_size, void* d_ws, size_t ws_size,
                              hipStream_t stream) {
    const int*   x  = (const int*)d_in[0];
    const float* L0 = (const float*)d_in[1];
    const float* p0 = (const float*)d_in[2];
    float* out = (float*)d_out;

    char* ws = (char*)d_ws;
    size_t off = 0;
    auto alloc = [&](size_t bytes) -> void* {
        off = (off + 255) & ~(size_t)255;
        void* p = ws + off;
        off += bytes;
        return p;
    };
    uint32_t* flags    = (uint32_t*)alloc(256);
    uint8_t*  widx     = (uint8_t*) alloc((size_t)TT * BB);
    uint32_t* cntg     = (uint32_t*)alloc((size_t)TT * OO * 4);
    u64*      winbits  = (u64*)     alloc((size_t)TT * OO * 4 * 8);
    u64*      postbits = (u64*)     alloc((size_t)TT * OO * 4 * 8);
    u64*      bitB     = (u64*)     alloc((size_t)TT * 4 * INN * 8);
    (void)ws_size;

    hipLaunchKernelGGL(k_zero, dim3(1), dim3(64), 0, stream, flags);
    hipLaunchKernelGGL(k_mono, dim3(NBLK), dim3(512), 0, stream,
                       x, L0, p0, flags, widx, cntg, winbits, postbits, bitB,
                       out, out + (size_t)INN * OO);
}